// Round 5
// baseline (1123.315 us; speedup 1.0000x reference)
//
#include <hip/hip_runtime.h>
#include <math.h>

#define NTOK 65536   // B*T = 8*8192
#define T_   8192
#define C_   512

typedef short short8 __attribute__((ext_vector_type(8)));
typedef float f32x4  __attribute__((ext_vector_type(4)));

#define GLDS(gp, lp) __builtin_amdgcn_global_load_lds( \
    (__attribute__((address_space(1))) void*)(void*)(gp), \
    (__attribute__((address_space(3))) void*)(lp), 16, 0, 0)

__device__ __forceinline__ unsigned short f2bf(float f){
  unsigned x = __float_as_uint(f);
  x += 0x7fffu + ((x >> 16) & 1u);
  return (unsigned short)(x >> 16);
}
__device__ __forceinline__ float bflo(unsigned p){ return __uint_as_float(p << 16); }
__device__ __forceinline__ float bfhi(unsigned p){ return __uint_as_float(p & 0xffff0000u); }
__device__ __forceinline__ float bfs(unsigned short u){ return __uint_as_float(((unsigned)u) << 16); }
__device__ __forceinline__ unsigned pack2(float a, float b){
  return (unsigned)f2bf(a) | ((unsigned)f2bf(b) << 16);
}

// ---------------- weight prep ----------------
__global__ __launch_bounds__(256) void k_convert(const float* __restrict__ src,
                                                 unsigned short* __restrict__ dst, int n){
  int i = blockIdx.x * 256 + threadIdx.x;
  if (i < n) dst[i] = f2bf(src[i]);
}
__global__ __launch_bounds__(256) void k_transpose_t(const float* __restrict__ src,
                                                     unsigned short* __restrict__ dst,
                                                     int R, int S){
  __shared__ float tile[64][65];
  int ntS = S >> 6;
  int tr = blockIdx.x / ntS, ts = blockIdx.x - tr * ntS;
  int tx = threadIdx.x & 63, tg = threadIdx.x >> 6;
  #pragma unroll
  for (int rr = tg; rr < 64; rr += 4)
    tile[rr][tx] = src[(size_t)(tr * 64 + rr) * S + ts * 64 + tx];
  __syncthreads();
  #pragma unroll
  for (int rr = tg; rr < 64; rr += 4)
    dst[(size_t)(ts * 64 + rr) * R + tr * 64 + tx] = f2bf(tile[tx][rr]);
}

// ---------------- layernorm: one block per row (C=512) ----------------
__global__ __launch_bounds__(256) void k_ln(const float* __restrict__ x,
                                            const float* __restrict__ g,
                                            const float* __restrict__ b,
                                            unsigned* __restrict__ outbf){
  int row = blockIdx.x;
  int t = threadIdx.x;
  float2 v = ((const float2*)(x + (size_t)row * C_))[t];
  float s = v.x + v.y, ss = v.x * v.x + v.y * v.y;
  #pragma unroll
  for (int o = 32; o; o >>= 1){ s += __shfl_down(s, o); ss += __shfl_down(ss, o); }
  __shared__ float red[8];
  if ((t & 63) == 0){ red[t >> 6] = s; red[4 + (t >> 6)] = ss; }
  __syncthreads();
  float S = red[0] + red[1] + red[2] + red[3];
  float Q = red[4] + red[5] + red[6] + red[7];
  float mu  = S * (1.0f / C_);
  float var = Q * (1.0f / C_) - mu * mu;
  float rs = rsqrtf(var + 1e-5f);
  float y0 = (v.x - mu) * rs * g[2*t]   + b[2*t];
  float y1 = (v.y - mu) * rs * g[2*t+1] + b[2*t+1];
  outbf[(size_t)row * 256 + t] = pack2(y0, y1);
}

// ---------------- depthwise causal conv K=3, coalesced, chunk-local out ----------------
__global__ __launch_bounds__(256) void k_conv(const unsigned* __restrict__ xn,
                                              const float* __restrict__ w,
                                              const float* __restrict__ bias,
                                              unsigned* __restrict__ loc,
                                              int base){
  size_t idx = (size_t)blockIdx.x * 256 + threadIdx.x;
  size_t n = (idx >> 8) + (size_t)base;
  int cp = (int)(idx & 255);
  int t = (int)(n & (T_ - 1));
  unsigned v0 = xn[n * 256 + cp];
  unsigned v1 = (t >= 1) ? xn[(n - 1) * 256 + cp] : 0u;
  unsigned v2 = (t >= 2) ? xn[(n - 2) * 256 + cp] : 0u;
  int c = cp * 2;
  float r0 = bias[c]     + bflo(v0)*w[c*3+2] + bflo(v1)*w[c*3+1] + bflo(v2)*w[c*3+0];
  float r1 = bias[c + 1] + bfhi(v0)*w[c*3+5] + bfhi(v1)*w[c*3+4] + bfhi(v2)*w[c*3+3];
  loc[idx] = pack2(r0, r1);
}

// ---------------- in-place row softmax over M=512, bf16 ----------------
__global__ __launch_bounds__(256) void k_softmax_ip(unsigned* __restrict__ sw){
  int row = blockIdx.x;
  int t = threadIdx.x;
  unsigned p = sw[(size_t)row * 256 + t];
  float vx = bflo(p), vy = bfhi(p);
  float mx = fmaxf(vx, vy);
  #pragma unroll
  for (int o = 32; o; o >>= 1) mx = fmaxf(mx, __shfl_xor(mx, o));
  __shared__ float red[8];
  int w = t >> 6;
  if ((t & 63) == 0) red[w] = mx;
  __syncthreads();
  mx = fmaxf(fmaxf(red[0], red[1]), fmaxf(red[2], red[3]));
  float e0 = __expf(vx - mx), e1 = __expf(vy - mx);
  float s = e0 + e1;
  #pragma unroll
  for (int o = 32; o; o >>= 1) s += __shfl_xor(s, o);
  if ((t & 63) == 0) red[4 + w] = s;
  __syncthreads();
  float inv = 1.0f / (red[4] + red[5] + red[6] + red[7]);
  sw[(size_t)row * 256 + t] = pack2(e0 * inv, e1 * inv);
}

// =================== 256x256 8-phase bf16 GEMM (T3+T4+T5, linear LDS) ===================
// A: M x K bf16 row-major, Bt: N x K bf16 (B^T). 512 thr = 8 waves (2Mx4N), BK=64.
// LDS 128KB: A[2][256][64], B[2][256][64]. Per phase: 16 MFMA (one C-quadrant x K=64).
// Quadrant order per K-tile: (qm,qn) = (0,0),(1,0),(0,1),(1,1).
// Free/land audit: A-qmh0(rows 0-63,128-191) read ph1,ph3 -> staged ph4+;
// A-qmh1 read ph2,ph4 -> staged ph5+; B read all 4 phases -> staged ph5+ (next tile's buf).
// Steady stages: ph1:A1h1(t+1) ph2:B1h0(t+1) ph3:B1h1(t+1) ph4:A0h0(t+2) ph5:A0h1(t+2)
// ph6:B0h0(t+2) ph7:B0h1(t+2) ph8:A1h0(t+3). vmcnt(2) at ph4/ph8 ends keeps newest
// half-tile in flight; everything a following phase reads has landed. EPI as before.
#define PH_PRE  { __builtin_amdgcn_s_barrier(); \
                  asm volatile("s_waitcnt lgkmcnt(0)" ::: "memory"); \
                  __builtin_amdgcn_sched_barrier(0); }
#define PH_END  __builtin_amdgcn_s_barrier();
#define VMW2    asm volatile("s_waitcnt vmcnt(2)" ::: "memory");
#define VMW0    asm volatile("s_waitcnt vmcnt(0)" ::: "memory");

template<int EPI, int K, int N>
__global__ __launch_bounds__(512, 2) void k_g256(const unsigned short* __restrict__ A,
                                                 const unsigned short* __restrict__ Bt,
                                                 void* __restrict__ out,
                                                 const float* __restrict__ bias,
                                                 const float* __restrict__ add){
  __shared__ char smem[131072];
  const int tid  = threadIdx.x;
  const int lane = tid & 63;
  const int w    = tid >> 6;
  const int wr   = w >> 2, wc = w & 3;
  const long brow = (long)blockIdx.x * 256;
  const long bcol = (long)blockIdx.y * 256;
  const int lr = lane & 15;
  const int lk = (lane >> 4) * 16;
  const int srow  = tid >> 3;          // staging: row within 64-row chunk (8 thr/row)
  const int sbyte = (tid & 7) * 16;
  const unsigned swb = (unsigned)(w * 1024);

  f32x4 acc[8][4];
  #pragma unroll
  for (int i = 0; i < 8; i++)
    #pragma unroll
    for (int j = 0; j < 4; j++){ f32x4 z = {0.f,0.f,0.f,0.f}; acc[i][j] = z; }

  const char* Ab = (const char*)(A + brow * (long)K);
  const char* Bb = (const char*)(Bt + bcol * (long)K);

  auto ST = [&](const char* g, int ldsoff, int row0, int kt){
    GLDS(g + ((long)(row0 + srow) * K + (long)kt * 64) * 2 + sbyte,
         smem + ldsoff + row0 * 128 + swb);
  };
  auto stA0 = [&](int b, int kt){ ST(Ab, b*32768, 0,  kt); ST(Ab, b*32768, 128, kt); };
  auto stA1 = [&](int b, int kt){ ST(Ab, b*32768, 64, kt); ST(Ab, b*32768, 192, kt); };
  auto stB0 = [&](int b, int kt){ ST(Bb, 65536+b*32768, 0,   kt); ST(Bb, 65536+b*32768, 64,  kt); };
  auto stB1 = [&](int b, int kt){ ST(Bb, 65536+b*32768, 128, kt); ST(Bb, 65536+b*32768, 192, kt); };

  short8 afr[4][2], bfr[2][2];
  auto RDA = [&](int b, int qm){
    #pragma unroll
    for (int mj = 0; mj < 4; mj++)
      #pragma unroll
      for (int kk = 0; kk < 2; kk++)
        afr[mj][kk] = *(const short8*)(smem + b*32768 +
            (wr*128 + (qm*4+mj)*16 + lr) * 128 + kk*64 + lk);
  };
  auto RDB = [&](int b, int qn){
    #pragma unroll
    for (int nj = 0; nj < 2; nj++)
      #pragma unroll
      for (int kk = 0; kk < 2; kk++)
        bfr[nj][kk] = *(const short8*)(smem + 65536 + b*32768 +
            (wc*64 + (qn*2+nj)*16 + lr) * 128 + kk*64 + lk);
  };
  auto MM = [&](int qm, int qn){
    __builtin_amdgcn_s_setprio(1);
    #pragma unroll
    for (int mj = 0; mj < 4; mj++)
      #pragma unroll
      for (int nj = 0; nj < 2; nj++)
        #pragma unroll
        for (int kk = 0; kk < 2; kk++)
          acc[qm*4+mj][qn*2+nj] =
            __builtin_amdgcn_mfma_f32_16x16x32_bf16(afr[mj][kk], bfr[nj][kk],
                                                    acc[qm*4+mj][qn*2+nj], 0, 0, 0);
    __builtin_amdgcn_s_setprio(0);
  };

  constexpr int nt    = K >> 6;     // K-tiles of 64 (even, >= 2)
  constexpr int niter = nt >> 1;

  // prologue: tile0 fully -> buf0; tile1 A-qmh0 -> buf1
  stA0(0, 0); stA1(0, 0); stB0(0, 0); stB1(0, 0);
  stA0(1, 1);
  VMW2;                       // tile0's 8 loads landed; tile1-A-h0 may fly
  __builtin_amdgcn_s_barrier();

  #pragma unroll 1
  for (int i = 0; i < niter; i++){
    const int t = 2 * i;
    // ph1 (buf0 qm0 qn0)
    RDA(0,0); RDB(0,0); stA1(1, t+1);
    PH_PRE; MM(0,0); PH_END;
    // ph2 (buf0 qm1 qn0)
    RDA(0,1); stB0(1, t+1);
    PH_PRE; MM(1,0); PH_END;
    // ph3 (buf0 qm0 qn1)
    RDA(0,0); RDB(0,1); stB1(1, t+1);
    PH_PRE; MM(0,1); PH_END;
    // ph4 (buf0 qm1 qn1) — drain so ph5 can read buf1 tile t+1
    RDA(0,1); if (t + 2 < nt) stA0(0, t+2);
    PH_PRE; MM(1,1);
    if (t + 2 < nt) { VMW2; } else { VMW0; }
    PH_END;
    // ph5 (buf1 qm0 qn0)
    RDA(1,0); RDB(1,0); if (t + 2 < nt) stA1(0, t+2);
    PH_PRE; MM(0,0); PH_END;
    // ph6 (buf1 qm1 qn0)
    RDA(1,1); if (t + 2 < nt) stB0(0, t+2);
    PH_PRE; MM(1,0); PH_END;
    // ph7 (buf1 qm0 qn1)
    RDA(1,0); RDB(1,1); if (t + 2 < nt) stB1(0, t+2);
    PH_PRE; MM(0,1); PH_END;
    // ph8 (buf1 qm1 qn1) — drain so next-iter ph1 can read buf0 tile t+2
    RDA(1,1); if (t + 3 < nt) stA0(1, t+3);
    PH_PRE; MM(1,1);
    if (i + 1 < niter){ if (t + 3 < nt) { VMW2; } else { VMW0; } }
    PH_END;
  }

  // epilogue: C/D layout col=lane&15, row=(lane>>4)*4+j
  const long rb = brow + wr * 128;
  const long cb = bcol + wc * 64;
  #pragma unroll
  for (int mi = 0; mi < 8; mi++){
    #pragma unroll
    for (int ni = 0; ni < 4; ni++){
      long rg0 = rb + mi * 16 + (lane >> 4) * 4;
      long cg  = cb + ni * 16 + lr;
      #pragma unroll
      for (int j = 0; j < 4; j++){
        long oi = (rg0 + j) * (long)N + cg;
        float v = acc[mi][ni][j];
        if (EPI == 1){
          ((unsigned short*)out)[oi] = f2bf(v);
        } else if (EPI == 3){
          v += bias[cg];
          v = 0.5f * v * (1.0f + erff(v * 0.70710678118654752f));
          ((unsigned short*)out)[oi] = f2bf(v);
        } else {
          v += bias[cg] + add[oi];
          ((float*)out)[oi] = v;
        }
      }
    }
  }
}

// ------- fused gates GEMM + sigmoid + gated combine + residual -> x2 (f32) -------
// 2-phase dbuf; epilogue reads precomputed loc (conv) + ctx; 128r x 64c of both halves.
__global__ __launch_bounds__(256, 2) void k_gatecomb(const unsigned short* __restrict__ A,
                                                     const unsigned short* __restrict__ Bt,
                                                     const float* __restrict__ gb,
                                                     const unsigned short* __restrict__ loc,
                                                     const unsigned short* __restrict__ ctx,
                                                     const float* __restrict__ x,
                                                     float* __restrict__ x2){
  __shared__ char smem[32768];   // [2] x { A 8KB | Bl 4KB | Bg 4KB }
  const int tid  = threadIdx.x;
  const int lane = tid & 63;
  const int w    = tid >> 6;
  const int wr   = w >> 1, wc = w & 1;
  const long brow = (long)blockIdx.x * 128;
  const int  bcol = blockIdx.y * 64;
  const int K = 512;

  f32x4 accL[4][2], accG[4][2];
  #pragma unroll
  for (int i = 0; i < 4; i++)
    #pragma unroll
    for (int j = 0; j < 2; j++){
      f32x4 z = {0.f,0.f,0.f,0.f}; accL[i][j] = z; accG[i][j] = z;
    }

  const char* Abase  = (const char*)(A + brow * (long)K);
  const char* Blbase = (const char*)(Bt + (long)bcol * K);
  const char* Bgbase = (const char*)(Bt + (long)(512 + bcol) * K);
  const int r0 = tid >> 2;
  const int c0 = (tid & 3) * 16;
  const unsigned wbase = (unsigned)(w * 1024);
  const int lr = lane & 15;
  const int lk = (lane >> 4) * 16;

  auto STAGE = [&](int buf, int k0){
    char* dA = smem + buf * 16384 + wbase;
    GLDS(Abase  + ((long)r0 * K + k0) * 2 + c0,        dA);
    GLDS(Abase  + ((long)(64 + r0) * K + k0) * 2 + c0, dA + 4096);
    GLDS(Blbase + ((long)r0 * K + k0) * 2 + c0,        dA + 8192);
    GLDS(Bgbase + ((long)r0 * K + k0) * 2 + c0,        dA + 12288);
  };
  auto COMPUTE = [&](int buf){
    const char* sAc  = smem + buf * 16384;
    const char* sBlc = sAc + 8192;
    const char* sBgc = sAc + 12288;
    short8 af[4], bl[2], bg[2];
    #pragma unroll
    for (int mi = 0; mi < 4; mi++)
      af[mi] = *(const short8*)(sAc + (wr * 64 + mi * 16 + lr) * 64 + lk);
    #pragma unroll
    for (int ni = 0; ni < 2; ni++){
      bl[ni] = *(const short8*)(sBlc + (wc * 32 + ni * 16 + lr) * 64 + lk);
      bg[ni] = *(const short8*)(sBgc + (wc * 32 + ni * 16 + lr) * 64 + lk);
    }
    #pragma unroll
    for (int mi = 0; mi < 4; mi++)
      #pragma unroll
      for (int ni = 0; ni < 2; ni++){
        accL[mi][ni] = __builtin_amdgcn_mfma_f32_16x16x32_bf16(af[mi], bl[ni], accL[mi][ni], 0, 0, 0);
        accG[mi][ni] = __builtin_amdgcn_mfma_f32_16x16x32_bf16(af[mi], bg[ni], accG[mi][ni], 0, 0, 0);
      }
  };

  STAGE(0, 0);
  __syncthreads();
  int cur = 0;
  for (int k0 = 32; k0 < K; k0 += 32){
    STAGE(cur ^ 1, k0);
    COMPUTE(cur);
    __syncthreads();
    cur ^= 1;
  }
  COMPUTE(cur);

  const long rbase = brow + wr * 64;
  const int  cb_   = bcol + wc * 32;
  #pragma unroll
  for (int mi = 0; mi < 4; mi++){
    #pragma unroll
    for (int ni = 0; ni < 2; ni++){
      long rg0 = rbase + mi * 16 + (lane >> 4) * 4;
      int  cg  = cb_ + ni * 16 + lr;
      float bL = gb[cg], bG = gb[512 + cg];
      #pragma unroll
      for (int j = 0; j < 4; j++){
        long rg = rg0 + j;
        long oi = rg * 512 + cg;
        float vL = 1.0f / (1.0f + __expf(-(accL[mi][ni][j] + bL)));
        float vG = 1.0f / (1.0f + __expf(-(accG[mi][ni][j] + bG)));
        x2[oi] = x[oi] + vL * bfs(loc[oi]) + vG * bfs(ctx[oi]);
      }
    }
  }
}

// ---------------- launch ----------------
extern "C" void kernel_launch(void* const* d_in, const int* in_sizes, int n_in,
                              void* d_out, int out_size, void* d_ws, size_t ws_size,
                              hipStream_t stream){
  const float* x      = (const float*)d_in[0];
  const float* conv_w = (const float*)d_in[1];
  const float* conv_b = (const float*)d_in[2];
  const float* mb     = (const float*)d_in[3];
  const float* gate_w = (const float*)d_in[4];
  const float* gate_b = (const float*)d_in[5];
  const float* w1     = (const float*)d_in[6];
  const float* b1     = (const float*)d_in[7];
  const float* w2     = (const float*)d_in[8];
  const float* b2     = (const float*)d_in[9];
  const float* ln1g   = (const float*)d_in[10];
  const float* ln1b   = (const float*)d_in[11];
  const float* ln2g   = (const float*)d_in[12];
  const float* ln2b   = (const float*)d_in[13];

  char* ws = (char*)d_ws;
  const size_t MB = 1024ull * 1024ull;
  unsigned short* mb_bf = (unsigned short*)(ws + 0);
  unsigned short* mbT   = (unsigned short*)(ws + 512 * 1024);
  unsigned short* gwT   = (unsigned short*)(ws + 1 * MB);
  unsigned short* w1T   = (unsigned short*)(ws + 2 * MB);
  unsigned short* w2T   = (unsigned short*)(ws + 4 * MB);
  unsigned short* xn    = (unsigned short*)(ws + 8 * MB);   // 64MB; reused as h
  char* region = ws + 72 * MB;

  // chunk tier (peak = 72MB + 3*S KB in middle phase; FFN f1 = 4*(S/2) KB <= 3*S KB)
  int S;
  if      (ws_size >= 264 * MB) S = 65536;
  else if (ws_size >= 120 * MB) S = 16384;
  else                          S = 4096;
  const int S2 = S / 2;
  const int NC  = NTOK / S;
  const int NC2 = NTOK / S2;

  unsigned short* loc_c = (unsigned short*)(region);
  unsigned short* ctx_c = (unsigned short*)(region + (size_t)S * 1024);
  unsigned short* sco_c = (unsigned short*)(region + (size_t)S * 2048);
  unsigned short* f1    = (unsigned short*)(region);   // reuses loc/ctx after middle phase

  // weight prep
  k_convert    <<<1024, 256, 0, stream>>>(mb, mb_bf, 512 * 512);
  k_transpose_t<<<  64, 256, 0, stream>>>(mb, mbT, 512, 512);
  k_transpose_t<<< 128, 256, 0, stream>>>(gate_w, gwT, 512, 1024);
  k_transpose_t<<< 256, 256, 0, stream>>>(w1, w1T, 512, 2048);
  k_transpose_t<<< 256, 256, 0, stream>>>(w2, w2T, 2048, 512);

  // LN1 -> xn (bf16, full)
  k_ln<<<NTOK, 256, 0, stream>>>(x, ln1g, ln1b, (unsigned*)xn);

  // middle phase, chunked over tokens
  for (int c = 0; c < NC; c++){
    const int base = c * S;
    const unsigned short* xnc = xn + (size_t)base * 512;
    // depthwise causal conv -> loc (bf16, chunk-local)
    k_conv<<<S, 256, 0, stream>>>((const unsigned*)xn, conv_w, conv_b,
                                  (unsigned*)loc_c, base);
    // scores = xn @ mb^T (bf16)
    k_g256<1, 512, 512><<<dim3(S / 256, 2), 512, 0, stream>>>(xnc, mb_bf, sco_c,
                                                              nullptr, nullptr);
    // softmax rows in-place
    k_softmax_ip<<<S, 256, 0, stream>>>((unsigned*)sco_c);
    // ctx = weights @ mb (bf16)
    k_g256<1, 512, 512><<<dim3(S / 256, 2), 512, 0, stream>>>(sco_c, mbT, ctx_c,
                                                              nullptr, nullptr);
    // gates GEMM + sigmoid + combine + residual -> x2 (f32, into d_out)
    k_gatecomb<<<dim3(S / 128, 8), 256, 0, stream>>>(xnc, gwT, gate_b,
                                                     loc_c, ctx_c,
                                                     x + (size_t)base * 512,
                                                     (float*)d_out + (size_t)base * 512);
  }

  // LN2: h = LN(x2) (bf16, reuse xn buffer)
  k_ln<<<NTOK, 256, 0, stream>>>((const float*)d_out, ln2g, ln2b, (unsigned*)xn);

  // FFN, chunked
  for (int c = 0; c < NC2; c++){
    const int base = c * S2;
    // f1 = gelu(h @ w1 + b1) (bf16)
    k_g256<3, 512, 2048><<<dim3(S2 / 256, 8), 512, 0, stream>>>(xn + (size_t)base * 512,
                                                                w1T, f1, b1, nullptr);
    // out = x2 + f1 @ w2 + b2 (f32, in-place per-element on d_out)
    k_g256<4, 2048, 512><<<dim3(S2 / 256, 2), 512, 0, stream>>>(f1, w2T,
                                                                (float*)d_out + (size_t)base * 512,
                                                                b2,
                                                                (const float*)d_out + (size_t)base * 512);
  }
}

// Round 6
// 940.136 us; speedup vs baseline: 1.1948x; 1.1948x over previous
//
#include <hip/hip_runtime.h>
#include <math.h>

#define NTOK 65536   // B*T = 8*8192
#define T_   8192
#define C_   512

typedef short short8 __attribute__((ext_vector_type(8)));
typedef float f32x4  __attribute__((ext_vector_type(4)));

#define GLDS(gp, lp) __builtin_amdgcn_global_load_lds( \
    (__attribute__((address_space(1))) void*)(void*)(gp), \
    (__attribute__((address_space(3))) void*)(lp), 16, 0, 0)

__device__ __forceinline__ unsigned short f2bf(float f){
  unsigned x = __float_as_uint(f);
  x += 0x7fffu + ((x >> 16) & 1u);
  return (unsigned short)(x >> 16);
}
__device__ __forceinline__ float bflo(unsigned p){ return __uint_as_float(p << 16); }
__device__ __forceinline__ float bfhi(unsigned p){ return __uint_as_float(p & 0xffff0000u); }
__device__ __forceinline__ float bfs(unsigned short u){ return __uint_as_float(((unsigned)u) << 16); }
__device__ __forceinline__ unsigned pack2(float a, float b){
  return (unsigned)f2bf(a) | ((unsigned)f2bf(b) << 16);
}

// ---------------- weight prep ----------------
__global__ __launch_bounds__(256) void k_convert(const float* __restrict__ src,
                                                 unsigned short* __restrict__ dst, int n){
  int i = blockIdx.x * 256 + threadIdx.x;
  if (i < n) dst[i] = f2bf(src[i]);
}
__global__ __launch_bounds__(256) void k_transpose_t(const float* __restrict__ src,
                                                     unsigned short* __restrict__ dst,
                                                     int R, int S){
  __shared__ float tile[64][65];
  int ntS = S >> 6;
  int tr = blockIdx.x / ntS, ts = blockIdx.x - tr * ntS;
  int tx = threadIdx.x & 63, tg = threadIdx.x >> 6;
  #pragma unroll
  for (int rr = tg; rr < 64; rr += 4)
    tile[rr][tx] = src[(size_t)(tr * 64 + rr) * S + ts * 64 + tx];
  __syncthreads();
  #pragma unroll
  for (int rr = tg; rr < 64; rr += 4)
    dst[(size_t)(ts * 64 + rr) * R + tr * 64 + tx] = f2bf(tile[tx][rr]);
}

// ---------------- layernorm: one block per row (C=512) ----------------
__global__ __launch_bounds__(256) void k_ln(const float* __restrict__ x,
                                            const float* __restrict__ g,
                                            const float* __restrict__ b,
                                            unsigned* __restrict__ outbf){
  int row = blockIdx.x;
  int t = threadIdx.x;
  float2 v = ((const float2*)(x + (size_t)row * C_))[t];
  float s = v.x + v.y, ss = v.x * v.x + v.y * v.y;
  #pragma unroll
  for (int o = 32; o; o >>= 1){ s += __shfl_down(s, o); ss += __shfl_down(ss, o); }
  __shared__ float red[8];
  if ((t & 63) == 0){ red[t >> 6] = s; red[4 + (t >> 6)] = ss; }
  __syncthreads();
  float S = red[0] + red[1] + red[2] + red[3];
  float Q = red[4] + red[5] + red[6] + red[7];
  float mu  = S * (1.0f / C_);
  float var = Q * (1.0f / C_) - mu * mu;
  float rs = rsqrtf(var + 1e-5f);
  float y0 = (v.x - mu) * rs * g[2*t]   + b[2*t];
  float y1 = (v.y - mu) * rs * g[2*t+1] + b[2*t+1];
  outbf[(size_t)row * 256 + t] = pack2(y0, y1);
}

// ---------------- depthwise causal conv K=3, coalesced, chunk-local out ----------------
__global__ __launch_bounds__(256) void k_conv(const unsigned* __restrict__ xn,
                                              const float* __restrict__ w,
                                              const float* __restrict__ bias,
                                              unsigned* __restrict__ loc,
                                              int base){
  size_t idx = (size_t)blockIdx.x * 256 + threadIdx.x;
  size_t n = (idx >> 8) + (size_t)base;
  int cp = (int)(idx & 255);
  int t = (int)(n & (T_ - 1));
  unsigned v0 = xn[n * 256 + cp];
  unsigned v1 = (t >= 1) ? xn[(n - 1) * 256 + cp] : 0u;
  unsigned v2 = (t >= 2) ? xn[(n - 2) * 256 + cp] : 0u;
  int c = cp * 2;
  float r0 = bias[c]     + bflo(v0)*w[c*3+2] + bflo(v1)*w[c*3+1] + bflo(v2)*w[c*3+0];
  float r1 = bias[c + 1] + bfhi(v0)*w[c*3+5] + bfhi(v1)*w[c*3+4] + bfhi(v2)*w[c*3+3];
  loc[idx] = pack2(r0, r1);
}

// ---------------- in-place row softmax over M=512, bf16 ----------------
__global__ __launch_bounds__(256) void k_softmax_ip(unsigned* __restrict__ sw){
  int row = blockIdx.x;
  int t = threadIdx.x;
  unsigned p = sw[(size_t)row * 256 + t];
  float vx = bflo(p), vy = bfhi(p);
  float mx = fmaxf(vx, vy);
  #pragma unroll
  for (int o = 32; o; o >>= 1) mx = fmaxf(mx, __shfl_xor(mx, o));
  __shared__ float red[8];
  int w = t >> 6;
  if ((t & 63) == 0) red[w] = mx;
  __syncthreads();
  mx = fmaxf(fmaxf(red[0], red[1]), fmaxf(red[2], red[3]));
  float e0 = __expf(vx - mx), e1 = __expf(vy - mx);
  float s = e0 + e1;
  #pragma unroll
  for (int o = 32; o; o >>= 1) s += __shfl_xor(s, o);
  if ((t & 63) == 0) red[4 + w] = s;
  __syncthreads();
  float inv = 1.0f / (red[4] + red[5] + red[6] + red[7]);
  sw[(size_t)row * 256 + t] = pack2(e0 * inv, e1 * inv);
}

// =================== 256x256 8-phase bf16 GEMM (T2+T3+T4+T5) ===================
// A: M x K bf16 row-major, Bt: N x K bf16 (B^T). 512 thr = 8 waves (2Mx4N), BK=64.
// LDS 128KB linear dest (GLDS requires it); T2 swizzle done by pre-swizzling the
// GLOBAL source column (sbyte ^ ((srow&7)<<4)) and applying the same XOR on every
// ds_read (row&7 == lr&7 since all other row terms are multiples of 8). Post-swizzle
// a wave's 64 b128 lanes cover all 8 16B slots uniformly -> LDS BW floor, ~0 conflicts.
// blockIdx.x = N-tile (small), blockIdx.y = M-tile: consecutive blocks share the A
// panel -> A fetched ~once (L2 reuse).
#define PH_PRE  { __builtin_amdgcn_s_barrier(); \
                  asm volatile("s_waitcnt lgkmcnt(0)" ::: "memory"); \
                  __builtin_amdgcn_sched_barrier(0); }
#define PH_END  __builtin_amdgcn_s_barrier();
#define VMW2    asm volatile("s_waitcnt vmcnt(2)" ::: "memory");
#define VMW0    asm volatile("s_waitcnt vmcnt(0)" ::: "memory");

template<int EPI, int K, int N>
__global__ __launch_bounds__(512, 2) void k_g256(const unsigned short* __restrict__ A,
                                                 const unsigned short* __restrict__ Bt,
                                                 void* __restrict__ out,
                                                 const float* __restrict__ bias,
                                                 const float* __restrict__ add){
  __shared__ char smem[131072];
  const int tid  = threadIdx.x;
  const int lane = tid & 63;
  const int w    = tid >> 6;
  const int wr   = w >> 2, wc = w & 3;
  const long brow = (long)blockIdx.y * 256;
  const long bcol = (long)blockIdx.x * 256;
  const int lr = lane & 15;
  const int lk = (lane >> 4) * 16;
  const int srow  = tid >> 3;          // staging: row within 64-row chunk (8 thr/row)
  const int sbyte = ((tid & 7) * 16) ^ ((srow & 7) << 4);   // T2 pre-swizzled source col
  const unsigned swb = (unsigned)(w * 1024);
  const int rsw = (lr & 7) << 4;       // T2 read-side XOR

  f32x4 acc[8][4];
  #pragma unroll
  for (int i = 0; i < 8; i++)
    #pragma unroll
    for (int j = 0; j < 4; j++){ f32x4 z = {0.f,0.f,0.f,0.f}; acc[i][j] = z; }

  const char* Ab = (const char*)(A + brow * (long)K);
  const char* Bb = (const char*)(Bt + bcol * (long)K);

  auto ST = [&](const char* g, int ldsoff, int row0, int kt){
    GLDS(g + ((long)(row0 + srow) * K + (long)kt * 64) * 2 + sbyte,
         smem + ldsoff + row0 * 128 + swb);
  };
  auto stA0 = [&](int b, int kt){ ST(Ab, b*32768, 0,  kt); ST(Ab, b*32768, 128, kt); };
  auto stA1 = [&](int b, int kt){ ST(Ab, b*32768, 64, kt); ST(Ab, b*32768, 192, kt); };
  auto stB0 = [&](int b, int kt){ ST(Bb, 65536+b*32768, 0,   kt); ST(Bb, 65536+b*32768, 64,  kt); };
  auto stB1 = [&](int b, int kt){ ST(Bb, 65536+b*32768, 128, kt); ST(Bb, 65536+b*32768, 192, kt); };

  short8 afr[4][2], bfr[2][2];
  auto RDA = [&](int b, int qm){
    #pragma unroll
    for (int mj = 0; mj < 4; mj++)
      #pragma unroll
      for (int kk = 0; kk < 2; kk++)
        afr[mj][kk] = *(const short8*)(smem + b*32768 +
            (wr*128 + (qm*4+mj)*16 + lr) * 128 + ((kk*64 + lk) ^ rsw));
  };
  auto RDB = [&](int b, int qn){
    #pragma unroll
    for (int nj = 0; nj < 2; nj++)
      #pragma unroll
      for (int kk = 0; kk < 2; kk++)
        bfr[nj][kk] = *(const short8*)(smem + 65536 + b*32768 +
            (wc*64 + (qn*2+nj)*16 + lr) * 128 + ((kk*64 + lk) ^ rsw));
  };
  auto MM = [&](int qm, int qn){
    __builtin_amdgcn_s_setprio(1);
    #pragma unroll
    for (int mj = 0; mj < 4; mj++)
      #pragma unroll
      for (int nj = 0; nj < 2; nj++)
        #pragma unroll
        for (int kk = 0; kk < 2; kk++)
          acc[qm*4+mj][qn*2+nj] =
            __builtin_amdgcn_mfma_f32_16x16x32_bf16(afr[mj][kk], bfr[nj][kk],
                                                    acc[qm*4+mj][qn*2+nj], 0, 0, 0);
    __builtin_amdgcn_s_setprio(0);
  };

  constexpr int nt    = K >> 6;     // K-tiles of 64 (even, >= 2)
  constexpr int niter = nt >> 1;

  // prologue: tile0 fully -> buf0; tile1 A-qmh0 -> buf1
  stA0(0, 0); stA1(0, 0); stB0(0, 0); stB1(0, 0);
  stA0(1, 1);
  VMW2;
  __builtin_amdgcn_s_barrier();

  #pragma unroll 1
  for (int i = 0; i < niter; i++){
    const int t = 2 * i;
    // ph1 (buf0 qm0 qn0)
    RDA(0,0); RDB(0,0); stA1(1, t+1);
    PH_PRE; MM(0,0); PH_END;
    // ph2 (buf0 qm1 qn0)
    RDA(0,1); stB0(1, t+1);
    PH_PRE; MM(1,0); PH_END;
    // ph3 (buf0 qm0 qn1)
    RDA(0,0); RDB(0,1); stB1(1, t+1);
    PH_PRE; MM(0,1); PH_END;
    // ph4 (buf0 qm1 qn1) — drain so ph5 can read buf1 tile t+1
    RDA(0,1); if (t + 2 < nt) stA0(0, t+2);
    PH_PRE; MM(1,1);
    if (t + 2 < nt) { VMW2; } else { VMW0; }
    PH_END;
    // ph5 (buf1 qm0 qn0)
    RDA(1,0); RDB(1,0); if (t + 2 < nt) stA1(0, t+2);
    PH_PRE; MM(0,0); PH_END;
    // ph6 (buf1 qm1 qn0)
    RDA(1,1); if (t + 2 < nt) stB0(0, t+2);
    PH_PRE; MM(1,0); PH_END;
    // ph7 (buf1 qm0 qn1)
    RDA(1,0); RDB(1,1); if (t + 2 < nt) stB1(0, t+2);
    PH_PRE; MM(0,1); PH_END;
    // ph8 (buf1 qm1 qn1) — drain so next-iter ph1 can read buf0 tile t+2
    RDA(1,1); if (t + 3 < nt) stA0(1, t+3);
    PH_PRE; MM(1,1);
    if (i + 1 < niter){ if (t + 3 < nt) { VMW2; } else { VMW0; } }
    PH_END;
  }

  // epilogue: C/D layout col=lane&15, row=(lane>>4)*4+j
  const long rb = brow + wr * 128;
  const long cb = bcol + wc * 64;
  #pragma unroll
  for (int mi = 0; mi < 8; mi++){
    #pragma unroll
    for (int ni = 0; ni < 4; ni++){
      long rg0 = rb + mi * 16 + (lane >> 4) * 4;
      long cg  = cb + ni * 16 + lr;
      #pragma unroll
      for (int j = 0; j < 4; j++){
        long oi = (rg0 + j) * (long)N + cg;
        float v = acc[mi][ni][j];
        if (EPI == 1){
          ((unsigned short*)out)[oi] = f2bf(v);
        } else if (EPI == 3){
          v += bias[cg];
          v = 0.5f * v * (1.0f + erff(v * 0.70710678118654752f));
          ((unsigned short*)out)[oi] = f2bf(v);
        } else {
          v += bias[cg] + add[oi];
          ((float*)out)[oi] = v;
        }
      }
    }
  }
}

// ------- fused gates GEMM + sigmoid + gated combine + residual -> x2 (f32) -------
// 2-phase dbuf; T2 swizzle (64B rows -> ^((r&3)<<4), both sides); blockIdx.x = col.
__global__ __launch_bounds__(256, 2) void k_gatecomb(const unsigned short* __restrict__ A,
                                                     const unsigned short* __restrict__ Bt,
                                                     const float* __restrict__ gb,
                                                     const unsigned short* __restrict__ loc,
                                                     const unsigned short* __restrict__ ctx,
                                                     const float* __restrict__ x,
                                                     float* __restrict__ x2){
  __shared__ char smem[32768];   // [2] x { A 8KB | Bl 4KB | Bg 4KB }
  const int tid  = threadIdx.x;
  const int lane = tid & 63;
  const int w    = tid >> 6;
  const int wr   = w >> 1, wc = w & 1;
  const long brow = (long)blockIdx.y * 128;
  const int  bcol = blockIdx.x * 64;
  const int K = 512;

  f32x4 accL[4][2], accG[4][2];
  #pragma unroll
  for (int i = 0; i < 4; i++)
    #pragma unroll
    for (int j = 0; j < 2; j++){
      f32x4 z = {0.f,0.f,0.f,0.f}; accL[i][j] = z; accG[i][j] = z;
    }

  const char* Abase  = (const char*)(A + brow * (long)K);
  const char* Blbase = (const char*)(Bt + (long)bcol * K);
  const char* Bgbase = (const char*)(Bt + (long)(512 + bcol) * K);
  const int r0 = tid >> 2;
  const int c0 = ((tid & 3) * 16) ^ ((r0 & 3) << 4);   // T2 pre-swizzled source col
  const unsigned wbase = (unsigned)(w * 1024);
  const int lr = lane & 15;
  const int lk = (lane >> 4) * 16;
  const int rsw = (lr & 3) << 4;                       // T2 read-side XOR

  auto STAGE = [&](int buf, int k0){
    char* dA = smem + buf * 16384 + wbase;
    GLDS(Abase  + ((long)r0 * K + k0) * 2 + c0,        dA);
    GLDS(Abase  + ((long)(64 + r0) * K + k0) * 2 + c0, dA + 4096);
    GLDS(Blbase + ((long)r0 * K + k0) * 2 + c0,        dA + 8192);
    GLDS(Bgbase + ((long)r0 * K + k0) * 2 + c0,        dA + 12288);
  };
  auto COMPUTE = [&](int buf){
    const char* sAc  = smem + buf * 16384;
    const char* sBlc = sAc + 8192;
    const char* sBgc = sAc + 12288;
    short8 af[4], bl[2], bg[2];
    #pragma unroll
    for (int mi = 0; mi < 4; mi++)
      af[mi] = *(const short8*)(sAc + (wr * 64 + mi * 16 + lr) * 64 + (lk ^ rsw));
    #pragma unroll
    for (int ni = 0; ni < 2; ni++){
      bl[ni] = *(const short8*)(sBlc + (wc * 32 + ni * 16 + lr) * 64 + (lk ^ rsw));
      bg[ni] = *(const short8*)(sBgc + (wc * 32 + ni * 16 + lr) * 64 + (lk ^ rsw));
    }
    #pragma unroll
    for (int mi = 0; mi < 4; mi++)
      #pragma unroll
      for (int ni = 0; ni < 2; ni++){
        accL[mi][ni] = __builtin_amdgcn_mfma_f32_16x16x32_bf16(af[mi], bl[ni], accL[mi][ni], 0, 0, 0);
        accG[mi][ni] = __builtin_amdgcn_mfma_f32_16x16x32_bf16(af[mi], bg[ni], accG[mi][ni], 0, 0, 0);
      }
  };

  STAGE(0, 0);
  __syncthreads();
  int cur = 0;
  for (int k0 = 32; k0 < K; k0 += 32){
    STAGE(cur ^ 1, k0);
    COMPUTE(cur);
    __syncthreads();
    cur ^= 1;
  }
  COMPUTE(cur);

  const long rbase = brow + wr * 64;
  const int  cb_   = bcol + wc * 32;
  #pragma unroll
  for (int mi = 0; mi < 4; mi++){
    #pragma unroll
    for (int ni = 0; ni < 2; ni++){
      long rg0 = rbase + mi * 16 + (lane >> 4) * 4;
      int  cg  = cb_ + ni * 16 + lr;
      float bL = gb[cg], bG = gb[512 + cg];
      #pragma unroll
      for (int j = 0; j < 4; j++){
        long rg = rg0 + j;
        long oi = rg * 512 + cg;
        float vL = 1.0f / (1.0f + __expf(-(accL[mi][ni][j] + bL)));
        float vG = 1.0f / (1.0f + __expf(-(accG[mi][ni][j] + bG)));
        x2[oi] = x[oi] + vL * bfs(loc[oi]) + vG * bfs(ctx[oi]);
      }
    }
  }
}

// ---------------- launch ----------------
extern "C" void kernel_launch(void* const* d_in, const int* in_sizes, int n_in,
                              void* d_out, int out_size, void* d_ws, size_t ws_size,
                              hipStream_t stream){
  const float* x      = (const float*)d_in[0];
  const float* conv_w = (const float*)d_in[1];
  const float* conv_b = (const float*)d_in[2];
  const float* mb     = (const float*)d_in[3];
  const float* gate_w = (const float*)d_in[4];
  const float* gate_b = (const float*)d_in[5];
  const float* w1     = (const float*)d_in[6];
  const float* b1     = (const float*)d_in[7];
  const float* w2     = (const float*)d_in[8];
  const float* b2     = (const float*)d_in[9];
  const float* ln1g   = (const float*)d_in[10];
  const float* ln1b   = (const float*)d_in[11];
  const float* ln2g   = (const float*)d_in[12];
  const float* ln2b   = (const float*)d_in[13];

  char* ws = (char*)d_ws;
  const size_t MB = 1024ull * 1024ull;
  unsigned short* mb_bf = (unsigned short*)(ws + 0);
  unsigned short* mbT   = (unsigned short*)(ws + 512 * 1024);
  unsigned short* gwT   = (unsigned short*)(ws + 1 * MB);
  unsigned short* w1T   = (unsigned short*)(ws + 2 * MB);
  unsigned short* w2T   = (unsigned short*)(ws + 4 * MB);
  unsigned short* xn    = (unsigned short*)(ws + 8 * MB);   // 64MB; reused as h
  char* region = ws + 72 * MB;

  // chunk tier (peak = 72MB + 3*S KB in middle phase; FFN f1 = 4*(S/2) KB <= 3*S KB)
  int S;
  if      (ws_size >= 264 * MB) S = 65536;
  else if (ws_size >= 120 * MB) S = 16384;
  else                          S = 4096;
  const int S2 = S / 2;
  const int NC  = NTOK / S;
  const int NC2 = NTOK / S2;

  unsigned short* loc_c = (unsigned short*)(region);
  unsigned short* ctx_c = (unsigned short*)(region + (size_t)S * 1024);
  unsigned short* sco_c = (unsigned short*)(region + (size_t)S * 2048);
  unsigned short* f1    = (unsigned short*)(region);   // reuses loc/ctx after middle phase

  // weight prep
  k_convert    <<<1024, 256, 0, stream>>>(mb, mb_bf, 512 * 512);
  k_transpose_t<<<  64, 256, 0, stream>>>(mb, mbT, 512, 512);
  k_transpose_t<<< 128, 256, 0, stream>>>(gate_w, gwT, 512, 1024);
  k_transpose_t<<< 256, 256, 0, stream>>>(w1, w1T, 512, 2048);
  k_transpose_t<<< 256, 256, 0, stream>>>(w2, w2T, 2048, 512);

  // LN1 -> xn (bf16, full)
  k_ln<<<NTOK, 256, 0, stream>>>(x, ln1g, ln1b, (unsigned*)xn);

  // middle phase, chunked over tokens
  for (int c = 0; c < NC; c++){
    const int base = c * S;
    const unsigned short* xnc = xn + (size_t)base * 512;
    // depthwise causal conv -> loc (bf16, chunk-local)
    k_conv<<<S, 256, 0, stream>>>((const unsigned*)xn, conv_w, conv_b,
                                  (unsigned*)loc_c, base);
    // scores = xn @ mb^T (bf16)
    k_g256<1, 512, 512><<<dim3(2, S / 256), 512, 0, stream>>>(xnc, mb_bf, sco_c,
                                                              nullptr, nullptr);
    // softmax rows in-place
    k_softmax_ip<<<S, 256, 0, stream>>>((unsigned*)sco_c);
    // ctx = weights @ mb (bf16)
    k_g256<1, 512, 512><<<dim3(2, S / 256), 512, 0, stream>>>(sco_c, mbT, ctx_c,
                                                              nullptr, nullptr);
    // gates GEMM + sigmoid + combine + residual -> x2 (f32, into d_out)
    k_gatecomb<<<dim3(8, S / 128), 256, 0, stream>>>(xnc, gwT, gate_b,
                                                     loc_c, ctx_c,
                                                     x + (size_t)base * 512,
                                                     (float*)d_out + (size_t)base * 512);
  }

  // LN2: h = LN(x2) (bf16, reuse xn buffer)
  k_ln<<<NTOK, 256, 0, stream>>>((const float*)d_out, ln2g, ln2b, (unsigned*)xn);

  // FFN, chunked
  for (int c = 0; c < NC2; c++){
    const int base = c * S2;
    // f1 = gelu(h @ w1 + b1) (bf16)
    k_g256<3, 512, 2048><<<dim3(8, S2 / 256), 512, 0, stream>>>(xn + (size_t)base * 512,
                                                                w1T, f1, b1, nullptr);
    // out = x2 + f1 @ w2 + b2 (f32, in-place per-element on d_out)
    k_g256<4, 2048, 512><<<dim3(2, S2 / 256), 512, 0, stream>>>(f1, w2T,
                                                                (float*)d_out + (size_t)base * 512,
                                                                b2,
                                                                (const float*)d_out + (size_t)base * 512);
  }
}

// Round 7
// 900.066 us; speedup vs baseline: 1.2480x; 1.0445x over previous
//
#include <hip/hip_runtime.h>
#include <math.h>

#define NTOK 65536   // B*T = 8*8192
#define T_   8192
#define C_   512

typedef short short8 __attribute__((ext_vector_type(8)));
typedef float f32x4  __attribute__((ext_vector_type(4)));

#define GLDS(gp, lp) __builtin_amdgcn_global_load_lds( \
    (__attribute__((address_space(1))) void*)(void*)(gp), \
    (__attribute__((address_space(3))) void*)(lp), 16, 0, 0)

__device__ __forceinline__ unsigned short f2bf(float f){
  unsigned x = __float_as_uint(f);
  x += 0x7fffu + ((x >> 16) & 1u);
  return (unsigned short)(x >> 16);
}
__device__ __forceinline__ float bflo(unsigned p){ return __uint_as_float(p << 16); }
__device__ __forceinline__ float bfhi(unsigned p){ return __uint_as_float(p & 0xffff0000u); }
__device__ __forceinline__ float bfs(unsigned short u){ return __uint_as_float(((unsigned)u) << 16); }
__device__ __forceinline__ unsigned pack2(float a, float b){
  return (unsigned)f2bf(a) | ((unsigned)f2bf(b) << 16);
}
// bijective XCD chunking (m204): consecutive remapped ids stay on one XCD
__device__ __forceinline__ int xcd_remap(int flat, int nwg){
  int q = nwg >> 3, r = nwg & 7;
  int xcd = flat & 7, idx = flat >> 3;
  return (xcd < r ? xcd * (q + 1) : r * (q + 1) + (xcd - r) * q) + idx;
}

// ---------------- weight prep ----------------
__global__ __launch_bounds__(256) void k_convert(const float* __restrict__ src,
                                                 unsigned short* __restrict__ dst, int n){
  int i = blockIdx.x * 256 + threadIdx.x;
  if (i < n) dst[i] = f2bf(src[i]);
}
__global__ __launch_bounds__(256) void k_transpose_t(const float* __restrict__ src,
                                                     unsigned short* __restrict__ dst,
                                                     int R, int S){
  __shared__ float tile[64][65];
  int ntS = S >> 6;
  int tr = blockIdx.x / ntS, ts = blockIdx.x - tr * ntS;
  int tx = threadIdx.x & 63, tg = threadIdx.x >> 6;
  #pragma unroll
  for (int rr = tg; rr < 64; rr += 4)
    tile[rr][tx] = src[(size_t)(tr * 64 + rr) * S + ts * 64 + tx];
  __syncthreads();
  #pragma unroll
  for (int rr = tg; rr < 64; rr += 4)
    dst[(size_t)(ts * 64 + rr) * R + tr * 64 + tx] = f2bf(tile[tx][rr]);
}

// ---------------- layernorm: one block per row (C=512) ----------------
__global__ __launch_bounds__(256) void k_ln(const float* __restrict__ x,
                                            const float* __restrict__ g,
                                            const float* __restrict__ b,
                                            unsigned* __restrict__ outbf){
  int row = blockIdx.x;
  int t = threadIdx.x;
  float2 v = ((const float2*)(x + (size_t)row * C_))[t];
  float s = v.x + v.y, ss = v.x * v.x + v.y * v.y;
  #pragma unroll
  for (int o = 32; o; o >>= 1){ s += __shfl_down(s, o); ss += __shfl_down(ss, o); }
  __shared__ float red[8];
  if ((t & 63) == 0){ red[t >> 6] = s; red[4 + (t >> 6)] = ss; }
  __syncthreads();
  float S = red[0] + red[1] + red[2] + red[3];
  float Q = red[4] + red[5] + red[6] + red[7];
  float mu  = S * (1.0f / C_);
  float var = Q * (1.0f / C_) - mu * mu;
  float rs = rsqrtf(var + 1e-5f);
  float y0 = (v.x - mu) * rs * g[2*t]   + b[2*t];
  float y1 = (v.y - mu) * rs * g[2*t+1] + b[2*t+1];
  outbf[(size_t)row * 256 + t] = pack2(y0, y1);
}

// ---------------- depthwise causal conv K=3, coalesced, chunk-local out ----------------
__global__ __launch_bounds__(256) void k_conv(const unsigned* __restrict__ xn,
                                              const float* __restrict__ w,
                                              const float* __restrict__ bias,
                                              unsigned* __restrict__ loc,
                                              int base){
  size_t idx = (size_t)blockIdx.x * 256 + threadIdx.x;
  size_t n = (idx >> 8) + (size_t)base;
  int cp = (int)(idx & 255);
  int t = (int)(n & (T_ - 1));
  unsigned v0 = xn[n * 256 + cp];
  unsigned v1 = (t >= 1) ? xn[(n - 1) * 256 + cp] : 0u;
  unsigned v2 = (t >= 2) ? xn[(n - 2) * 256 + cp] : 0u;
  int c = cp * 2;
  float r0 = bias[c]     + bflo(v0)*w[c*3+2] + bflo(v1)*w[c*3+1] + bflo(v2)*w[c*3+0];
  float r1 = bias[c + 1] + bfhi(v0)*w[c*3+5] + bfhi(v1)*w[c*3+4] + bfhi(v2)*w[c*3+3];
  loc[idx] = pack2(r0, r1);
}

// ---------------- in-place row softmax over M=512, bf16 ----------------
__global__ __launch_bounds__(256) void k_softmax_ip(unsigned* __restrict__ sw){
  int row = blockIdx.x;
  int t = threadIdx.x;
  unsigned p = sw[(size_t)row * 256 + t];
  float vx = bflo(p), vy = bfhi(p);
  float mx = fmaxf(vx, vy);
  #pragma unroll
  for (int o = 32; o; o >>= 1) mx = fmaxf(mx, __shfl_xor(mx, o));
  __shared__ float red[8];
  int w = t >> 6;
  if ((t & 63) == 0) red[w] = mx;
  __syncthreads();
  mx = fmaxf(fmaxf(red[0], red[1]), fmaxf(red[2], red[3]));
  float e0 = __expf(vx - mx), e1 = __expf(vy - mx);
  float s = e0 + e1;
  #pragma unroll
  for (int o = 32; o; o >>= 1) s += __shfl_xor(s, o);
  if ((t & 63) == 0) red[4 + w] = s;
  __syncthreads();
  float inv = 1.0f / (red[4] + red[5] + red[6] + red[7]);
  sw[(size_t)row * 256 + t] = pack2(e0 * inv, e1 * inv);
}

// =================== 256x256 8-phase bf16 GEMM (T1+T2+T3+T4+T5) ===================
#define PH_PRE  { __builtin_amdgcn_s_barrier(); \
                  asm volatile("s_waitcnt lgkmcnt(0)" ::: "memory"); \
                  __builtin_amdgcn_sched_barrier(0); }
#define PH_END  __builtin_amdgcn_s_barrier();
#define VMW2    asm volatile("s_waitcnt vmcnt(2)" ::: "memory");
#define VMW0    asm volatile("s_waitcnt vmcnt(0)" ::: "memory");

template<int EPI, int K, int N>
__global__ __launch_bounds__(512, 2) void k_g256(const unsigned short* __restrict__ A,
                                                 const unsigned short* __restrict__ Bt,
                                                 void* __restrict__ out,
                                                 const float* __restrict__ bias,
                                                 const float* __restrict__ add){
  __shared__ char smem[131072];
  const int tid  = threadIdx.x;
  const int lane = tid & 63;
  const int w    = tid >> 6;
  const int wr   = w >> 2, wc = w & 3;
  const int nwg  = gridDim.x * gridDim.y;
  const int wgid = xcd_remap(blockIdx.y * gridDim.x + blockIdx.x, nwg);
  const long bcol = (long)(wgid % gridDim.x) * 256;
  const long brow = (long)(wgid / gridDim.x) * 256;
  const int lr = lane & 15;
  const int lk = (lane >> 4) * 16;
  const int srow  = tid >> 3;
  const int sbyte = ((tid & 7) * 16) ^ ((srow & 7) << 4);   // T2 pre-swizzled source col
  const unsigned swb = (unsigned)(w * 1024);
  const int rsw = (lr & 7) << 4;                            // T2 read-side XOR

  f32x4 acc[8][4];
  #pragma unroll
  for (int i = 0; i < 8; i++)
    #pragma unroll
    for (int j = 0; j < 4; j++){ f32x4 z = {0.f,0.f,0.f,0.f}; acc[i][j] = z; }

  const char* Ab = (const char*)(A + brow * (long)K);
  const char* Bb = (const char*)(Bt + bcol * (long)K);

  auto ST = [&](const char* g, int ldsoff, int row0, int kt){
    GLDS(g + ((long)(row0 + srow) * K + (long)kt * 64) * 2 + sbyte,
         smem + ldsoff + row0 * 128 + swb);
  };
  auto stA0 = [&](int b, int kt){ ST(Ab, b*32768, 0,  kt); ST(Ab, b*32768, 128, kt); };
  auto stA1 = [&](int b, int kt){ ST(Ab, b*32768, 64, kt); ST(Ab, b*32768, 192, kt); };
  auto stB0 = [&](int b, int kt){ ST(Bb, 65536+b*32768, 0,   kt); ST(Bb, 65536+b*32768, 64,  kt); };
  auto stB1 = [&](int b, int kt){ ST(Bb, 65536+b*32768, 128, kt); ST(Bb, 65536+b*32768, 192, kt); };

  short8 afr[4][2], bfr[2][2];
  auto RDA = [&](int b, int qm){
    #pragma unroll
    for (int mj = 0; mj < 4; mj++)
      #pragma unroll
      for (int kk = 0; kk < 2; kk++)
        afr[mj][kk] = *(const short8*)(smem + b*32768 +
            (wr*128 + (qm*4+mj)*16 + lr) * 128 + ((kk*64 + lk) ^ rsw));
  };
  auto RDB = [&](int b, int qn){
    #pragma unroll
    for (int nj = 0; nj < 2; nj++)
      #pragma unroll
      for (int kk = 0; kk < 2; kk++)
        bfr[nj][kk] = *(const short8*)(smem + 65536 + b*32768 +
            (wc*64 + (qn*2+nj)*16 + lr) * 128 + ((kk*64 + lk) ^ rsw));
  };
  auto MM = [&](int qm, int qn){
    __builtin_amdgcn_s_setprio(1);
    #pragma unroll
    for (int mj = 0; mj < 4; mj++)
      #pragma unroll
      for (int nj = 0; nj < 2; nj++)
        #pragma unroll
        for (int kk = 0; kk < 2; kk++)
          acc[qm*4+mj][qn*2+nj] =
            __builtin_amdgcn_mfma_f32_16x16x32_bf16(afr[mj][kk], bfr[nj][kk],
                                                    acc[qm*4+mj][qn*2+nj], 0, 0, 0);
    __builtin_amdgcn_s_setprio(0);
  };

  constexpr int nt    = K >> 6;
  constexpr int niter = nt >> 1;

  stA0(0, 0); stA1(0, 0); stB0(0, 0); stB1(0, 0);
  stA0(1, 1);
  VMW2;
  __builtin_amdgcn_s_barrier();

  #pragma unroll 1
  for (int i = 0; i < niter; i++){
    const int t = 2 * i;
    RDA(0,0); RDB(0,0); stA1(1, t+1);
    PH_PRE; MM(0,0); PH_END;
    RDA(0,1); stB0(1, t+1);
    PH_PRE; MM(1,0); PH_END;
    RDA(0,0); RDB(0,1); stB1(1, t+1);
    PH_PRE; MM(0,1); PH_END;
    RDA(0,1); if (t + 2 < nt) stA0(0, t+2);
    PH_PRE; MM(1,1);
    if (t + 2 < nt) { VMW2; } else { VMW0; }
    PH_END;
    RDA(1,0); RDB(1,0); if (t + 2 < nt) stA1(0, t+2);
    PH_PRE; MM(0,0); PH_END;
    RDA(1,1); if (t + 2 < nt) stB0(0, t+2);
    PH_PRE; MM(1,0); PH_END;
    RDA(1,0); RDB(1,1); if (t + 2 < nt) stB1(0, t+2);
    PH_PRE; MM(0,1); PH_END;
    RDA(1,1); if (t + 3 < nt) stA0(1, t+3);
    PH_PRE; MM(1,1);
    if (i + 1 < niter){ if (t + 3 < nt) { VMW2; } else { VMW0; } }
    PH_END;
  }

  const long rb = brow + wr * 128;
  const long cb = bcol + wc * 64;
  #pragma unroll
  for (int mi = 0; mi < 8; mi++){
    #pragma unroll
    for (int ni = 0; ni < 4; ni++){
      long rg0 = rb + mi * 16 + (lane >> 4) * 4;
      long cg  = cb + ni * 16 + lr;
      #pragma unroll
      for (int j = 0; j < 4; j++){
        long oi = (rg0 + j) * (long)N + cg;
        float v = acc[mi][ni][j];
        if (EPI == 1){
          ((unsigned short*)out)[oi] = f2bf(v);
        } else if (EPI == 3){
          v += bias[cg];
          v = 0.5f * v * (1.0f + erff(v * 0.70710678118654752f));
          ((unsigned short*)out)[oi] = f2bf(v);
        } else {
          v += bias[cg] + add[oi];
          ((float*)out)[oi] = v;
        }
      }
    }
  }
}

// ===== fused gates GEMM (8-phase) + sigmoid + gated combine + residual -> x2 =====
// Tile: 256 rows x 128 cols of BOTH gate halves (lg at bcol, gg at 512+bcol).
// Mirrors k_g256's staging-slot schedule exactly: stB0->stBL, stB1->stBG.
// LDS per buf: A 32KB | BL 16KB | BG 16KB (A at b*32768, B at 65536+b*32768+h*16384).
// acc[8][2][2] = 128 regs. Grid (4, S/256). Epilogue combines loc/ctx/x -> x2.
__global__ __launch_bounds__(512, 2) void k_gc256(const unsigned short* __restrict__ A,
                                                  const unsigned short* __restrict__ Bt,
                                                  const float* __restrict__ gb,
                                                  const unsigned short* __restrict__ loc,
                                                  const unsigned short* __restrict__ ctx,
                                                  const float* __restrict__ x,
                                                  float* __restrict__ x2){
  __shared__ char smem[131072];
  const int tid  = threadIdx.x;
  const int lane = tid & 63;
  const int w    = tid >> 6;
  const int wr   = w >> 2, wc = w & 3;
  const int nwg  = gridDim.x * gridDim.y;
  const int wgid = xcd_remap(blockIdx.y * gridDim.x + blockIdx.x, nwg);
  const int  bcol = (wgid % gridDim.x) * 128;
  const long brow = (long)(wgid / gridDim.x) * 256;
  const int K = 512;
  const int lr = lane & 15;
  const int lk = (lane >> 4) * 16;
  const int srow  = tid >> 3;
  const int sbyte = ((tid & 7) * 16) ^ ((srow & 7) << 4);
  const unsigned swb = (unsigned)(w * 1024);
  const int rsw = (lr & 7) << 4;

  f32x4 acc[8][2][2];
  #pragma unroll
  for (int i = 0; i < 8; i++)
    #pragma unroll
    for (int j = 0; j < 2; j++)
      #pragma unroll
      for (int h = 0; h < 2; h++){ f32x4 z = {0.f,0.f,0.f,0.f}; acc[i][j][h] = z; }

  const char* Ab  = (const char*)(A + brow * (long)K);
  const char* BbL = (const char*)(Bt + (long)bcol * K);
  const char* BbG = (const char*)(Bt + (long)(512 + bcol) * K);

  auto ST = [&](const char* g, int ldsoff, int row0, int kt){
    GLDS(g + ((long)(row0 + srow) * K + (long)kt * 64) * 2 + sbyte,
         smem + ldsoff + row0 * 128 + swb);
  };
  auto stA0 = [&](int b, int kt){ ST(Ab, b*32768, 0,  kt); ST(Ab, b*32768, 128, kt); };
  auto stA1 = [&](int b, int kt){ ST(Ab, b*32768, 64, kt); ST(Ab, b*32768, 192, kt); };
  auto stBL = [&](int b, int kt){ ST(BbL, 65536+b*32768,       0, kt); ST(BbL, 65536+b*32768,       64, kt); };
  auto stBG = [&](int b, int kt){ ST(BbG, 65536+b*32768+16384, 0, kt); ST(BbG, 65536+b*32768+16384, 64, kt); };

  short8 afr[4][2], bfr[2][2];
  auto RDA = [&](int b, int qm){
    #pragma unroll
    for (int mj = 0; mj < 4; mj++)
      #pragma unroll
      for (int kk = 0; kk < 2; kk++)
        afr[mj][kk] = *(const short8*)(smem + b*32768 +
            (wr*128 + (qm*4+mj)*16 + lr) * 128 + ((kk*64 + lk) ^ rsw));
  };
  auto RDB = [&](int b, int h){
    #pragma unroll
    for (int nj = 0; nj < 2; nj++)
      #pragma unroll
      for (int kk = 0; kk < 2; kk++)
        bfr[nj][kk] = *(const short8*)(smem + 65536 + b*32768 + h*16384 +
            (wc*32 + nj*16 + lr) * 128 + ((kk*64 + lk) ^ rsw));
  };
  auto MM = [&](int qm, int h){
    __builtin_amdgcn_s_setprio(1);
    #pragma unroll
    for (int mj = 0; mj < 4; mj++)
      #pragma unroll
      for (int nj = 0; nj < 2; nj++)
        #pragma unroll
        for (int kk = 0; kk < 2; kk++)
          acc[qm*4+mj][nj][h] =
            __builtin_amdgcn_mfma_f32_16x16x32_bf16(afr[mj][kk], bfr[nj][kk],
                                                    acc[qm*4+mj][nj][h], 0, 0, 0);
    __builtin_amdgcn_s_setprio(0);
  };

  constexpr int nt = 8, niter = 4;   // K=512

  stA0(0, 0); stA1(0, 0); stBL(0, 0); stBG(0, 0);
  stA0(1, 1);
  VMW2;
  __builtin_amdgcn_s_barrier();

  #pragma unroll 1
  for (int i = 0; i < niter; i++){
    const int t = 2 * i;
    // ph1 (buf0 qm0 L)
    RDA(0,0); RDB(0,0); stA1(1, t+1);
    PH_PRE; MM(0,0); PH_END;
    // ph2 (buf0 qm1 L)
    RDA(0,1); stBL(1, t+1);
    PH_PRE; MM(1,0); PH_END;
    // ph3 (buf0 qm0 G)
    RDA(0,0); RDB(0,1); stBG(1, t+1);
    PH_PRE; MM(0,1); PH_END;
    // ph4 (buf0 qm1 G)
    RDA(0,1); if (t + 2 < nt) stA0(0, t+2);
    PH_PRE; MM(1,1);
    if (t + 2 < nt) { VMW2; } else { VMW0; }
    PH_END;
    // ph5 (buf1 qm0 L)
    RDA(1,0); RDB(1,0); if (t + 2 < nt) stA1(0, t+2);
    PH_PRE; MM(0,0); PH_END;
    // ph6 (buf1 qm1 L)
    RDA(1,1); if (t + 2 < nt) stBL(0, t+2);
    PH_PRE; MM(1,0); PH_END;
    // ph7 (buf1 qm0 G)
    RDA(1,0); RDB(1,1); if (t + 2 < nt) stBG(0, t+2);
    PH_PRE; MM(0,1); PH_END;
    // ph8 (buf1 qm1 G)
    RDA(1,1); if (t + 3 < nt) stA0(1, t+3);
    PH_PRE; MM(1,1);
    if (i + 1 < niter){ if (t + 3 < nt) { VMW2; } else { VMW0; } }
    PH_END;
  }

  const long rbase = brow + wr * 128;
  const int  cb_   = bcol + wc * 32;
  #pragma unroll
  for (int mi = 0; mi < 8; mi++){
    #pragma unroll
    for (int ni = 0; ni < 2; ni++){
      long rg0 = rbase + mi * 16 + (lane >> 4) * 4;
      int  cg  = cb_ + ni * 16 + lr;
      float bL = gb[cg], bG = gb[512 + cg];
      #pragma unroll
      for (int j = 0; j < 4; j++){
        long rg = rg0 + j;
        long oi = rg * 512 + cg;
        float vL = 1.0f / (1.0f + __expf(-(acc[mi][ni][0][j] + bL)));
        float vG = 1.0f / (1.0f + __expf(-(acc[mi][ni][1][j] + bG)));
        x2[oi] = x[oi] + vL * bfs(loc[oi]) + vG * bfs(ctx[oi]);
      }
    }
  }
}

// ---------------- launch ----------------
extern "C" void kernel_launch(void* const* d_in, const int* in_sizes, int n_in,
                              void* d_out, int out_size, void* d_ws, size_t ws_size,
                              hipStream_t stream){
  const float* x      = (const float*)d_in[0];
  const float* conv_w = (const float*)d_in[1];
  const float* conv_b = (const float*)d_in[2];
  const float* mb     = (const float*)d_in[3];
  const float* gate_w = (const float*)d_in[4];
  const float* gate_b = (const float*)d_in[5];
  const float* w1     = (const float*)d_in[6];
  const float* b1     = (const float*)d_in[7];
  const float* w2     = (const float*)d_in[8];
  const float* b2     = (const float*)d_in[9];
  const float* ln1g   = (const float*)d_in[10];
  const float* ln1b   = (const float*)d_in[11];
  const float* ln2g   = (const float*)d_in[12];
  const float* ln2b   = (const float*)d_in[13];

  char* ws = (char*)d_ws;
  const size_t MB = 1024ull * 1024ull;
  unsigned short* mb_bf = (unsigned short*)(ws + 0);
  unsigned short* mbT   = (unsigned short*)(ws + 512 * 1024);
  unsigned short* gwT   = (unsigned short*)(ws + 1 * MB);
  unsigned short* w1T   = (unsigned short*)(ws + 2 * MB);
  unsigned short* w2T   = (unsigned short*)(ws + 4 * MB);
  unsigned short* xn    = (unsigned short*)(ws + 8 * MB);   // 64MB; reused as h
  char* region = ws + 72 * MB;

  int S;
  if      (ws_size >= 264 * MB) S = 65536;
  else if (ws_size >= 120 * MB) S = 16384;
  else                          S = 4096;
  const int S2 = S / 2;
  const int NC  = NTOK / S;
  const int NC2 = NTOK / S2;

  unsigned short* loc_c = (unsigned short*)(region);
  unsigned short* ctx_c = (unsigned short*)(region + (size_t)S * 1024);
  unsigned short* sco_c = (unsigned short*)(region + (size_t)S * 2048);
  unsigned short* f1    = (unsigned short*)(region);

  // weight prep
  k_convert    <<<1024, 256, 0, stream>>>(mb, mb_bf, 512 * 512);
  k_transpose_t<<<  64, 256, 0, stream>>>(mb, mbT, 512, 512);
  k_transpose_t<<< 128, 256, 0, stream>>>(gate_w, gwT, 512, 1024);
  k_transpose_t<<< 256, 256, 0, stream>>>(w1, w1T, 512, 2048);
  k_transpose_t<<< 256, 256, 0, stream>>>(w2, w2T, 2048, 512);

  // LN1 -> xn (bf16, full)
  k_ln<<<NTOK, 256, 0, stream>>>(x, ln1g, ln1b, (unsigned*)xn);

  // middle phase, chunked over tokens
  for (int c = 0; c < NC; c++){
    const int base = c * S;
    const unsigned short* xnc = xn + (size_t)base * 512;
    k_conv<<<S, 256, 0, stream>>>((const unsigned*)xn, conv_w, conv_b,
                                  (unsigned*)loc_c, base);
    // scores = xn @ mb^T (bf16)
    k_g256<1, 512, 512><<<dim3(2, S / 256), 512, 0, stream>>>(xnc, mb_bf, sco_c,
                                                              nullptr, nullptr);
    k_softmax_ip<<<S, 256, 0, stream>>>((unsigned*)sco_c);
    // ctx = weights @ mb (bf16)
    k_g256<1, 512, 512><<<dim3(2, S / 256), 512, 0, stream>>>(sco_c, mbT, ctx_c,
                                                              nullptr, nullptr);
    // gates GEMM (8-phase) + sigmoid + combine + residual -> x2 (f32, into d_out)
    k_gc256<<<dim3(4, S / 256), 512, 0, stream>>>(xnc, gwT, gate_b,
                                                  loc_c, ctx_c,
                                                  x + (size_t)base * 512,
                                                  (float*)d_out + (size_t)base * 512);
  }

  // LN2: h = LN(x2) (bf16, reuse xn buffer)
  k_ln<<<NTOK, 256, 0, stream>>>((const float*)d_out, ln2g, ln2b, (unsigned*)xn);

  // FFN, chunked
  for (int c = 0; c < NC2; c++){
    const int base = c * S2;
    // f1 = gelu(h @ w1 + b1) (bf16)
    k_g256<3, 512, 2048><<<dim3(8, S2 / 256), 512, 0, stream>>>(xn + (size_t)base * 512,
                                                                w1T, f1, b1, nullptr);
    // out = x2 + f1 @ w2 + b2 (f32, in-place per-element on d_out)
    k_g256<4, 2048, 512><<<dim3(2, S2 / 256), 512, 0, stream>>>(f1, w2T,
                                                                (float*)d_out + (size_t)base * 512,
                                                                b2,
                                                                (const float*)d_out + (size_t)base * 512);
  }
}